// Round 1
// baseline (2748.148 us; speedup 1.0000x reference)
//
#include <hip/hip_runtime.h>
#include <math.h>

#define H_   1024
#define HR_  256
#define DI_  2048
#define NS_  16
#define KC_  4
#define DTR_ 64
#define B_   4
#define L_   1024
#define ROWS (B_*L_)   // 4096
#define H3_  3072

__device__ __forceinline__ float silu_f(float v) { return v / (1.f + __expf(-v)); }

// ---------------------------------------------------------------------------
// K1: ada = silu(t) @ ada_w + ada_b      (B,3H)
// grid (3072/256, B), block 256
// ---------------------------------------------------------------------------
__global__ __launch_bounds__(256) void ada_kernel(
    const float* __restrict__ t, const float* __restrict__ ada_w,
    const float* __restrict__ ada_b, float* __restrict__ ada)
{
    int b   = blockIdx.y;
    int col = blockIdx.x * 256 + threadIdx.x;
    __shared__ float st[H_];
    for (int i = threadIdx.x; i < H_; i += 256) {
        float v = t[b * H_ + i];
        st[i] = silu_f(v);
    }
    __syncthreads();
    float acc = 0.f;
    for (int k = 0; k < H_; ++k)
        acc = fmaf(st[k], ada_w[(size_t)k * H3_ + col], acc);
    ada[b * H3_ + col] = acc + ada_b[col];
}

// ---------------------------------------------------------------------------
// K2: x1 = LN(x) * (1+scale) + shift     (B,L,H)
// one block (256 thr) per row; grid ROWS
// ---------------------------------------------------------------------------
__global__ __launch_bounds__(256) void ln_mod_kernel(
    const float* __restrict__ x, const float* __restrict__ ada,
    float* __restrict__ x1)
{
    int row = blockIdx.x;
    int b   = row >> 10;               // L = 1024
    const float* xr = x + (size_t)row * H_;
    float4 v = ((const float4*)xr)[threadIdx.x];
    float s  = v.x + v.y + v.z + v.w;
    float s2 = v.x*v.x + v.y*v.y + v.z*v.z + v.w*v.w;

    __shared__ float red[8];
    int wave = threadIdx.x >> 6, lane = threadIdx.x & 63;
    #pragma unroll
    for (int off = 32; off; off >>= 1) {
        s  += __shfl_down(s,  off);
        s2 += __shfl_down(s2, off);
    }
    if (lane == 0) { red[wave] = s; red[4 + wave] = s2; }
    __syncthreads();
    float ts  = red[0] + red[1] + red[2] + red[3];
    float ts2 = red[4] + red[5] + red[6] + red[7];
    float mu  = ts  * (1.f / H_);
    float var = ts2 * (1.f / H_) - mu * mu;
    float inv = rsqrtf(var + 1e-6f);

    const float* sh = ada + b * H3_;       // shift at 0, scale at 1024
    int i = threadIdx.x * 4;
    float4 sh4 = *(const float4*)&sh[i];
    float4 sc4 = *(const float4*)&sh[H_ + i];
    float4 o;
    o.x = (v.x - mu) * inv * (1.f + sc4.x) + sh4.x;
    o.y = (v.y - mu) * inv * (1.f + sc4.y) + sh4.y;
    o.z = (v.z - mu) * inv * (1.f + sc4.z) + sh4.z;
    o.w = (v.w - mu) * inv * (1.f + sc4.w) + sh4.w;
    ((float4*)(x1 + (size_t)row * H_))[threadIdx.x] = o;
}

// ---------------------------------------------------------------------------
// K3: generic fp32 GEMM, C = act(A[M,lda] @ W[K,N] + bias)
// 128x128 tile, BK=16, 256 threads, 8x8 micro-tile
// ACT: 0 none, 1 silu, 2 softplus, 3 silu*C (gate), 4 x + alpha*v (final)
// ---------------------------------------------------------------------------
template<int ACT>
__global__ __launch_bounds__(256) void gemm_kernel(
    const float* __restrict__ A, int lda,
    const float* __restrict__ W, const float* __restrict__ bias,
    float* __restrict__ C, int ldc,
    int M, int N, int K,
    const float* __restrict__ E0, const float* __restrict__ E1)
{
    __shared__ float As[16][132];
    __shared__ float Ws[16][132];
    int tid = threadIdx.x;
    int m0 = blockIdx.x * 128;
    int n0 = blockIdx.y * 128;
    int ty = tid >> 4, tx = tid & 15;
    float acc[8][8];
    #pragma unroll
    for (int i = 0; i < 8; ++i)
        #pragma unroll
        for (int j = 0; j < 8; ++j) acc[i][j] = 0.f;

    int arow = tid >> 2;            // 0..63
    int ak4  = (tid & 3) * 4;       // 0,4,8,12
    int wk   = tid >> 5;            // 0..7
    int wn4  = (tid & 31) * 4;      // 0..124

    for (int k0 = 0; k0 < K; k0 += 16) {
        __syncthreads();
        #pragma unroll
        for (int r = 0; r < 2; ++r) {
            int row = arow + r * 64;
            const float* src = A + (size_t)(m0 + row) * lda + k0 + ak4;
            float4 v = *(const float4*)src;
            As[ak4 + 0][row] = v.x; As[ak4 + 1][row] = v.y;
            As[ak4 + 2][row] = v.z; As[ak4 + 3][row] = v.w;
        }
        #pragma unroll
        for (int r = 0; r < 2; ++r) {
            int kk  = wk + r * 8;
            int col = n0 + wn4;
            const float* src = W + (size_t)(k0 + kk) * N + col;
            float4 v;
            if (col + 3 < N) v = *(const float4*)src;
            else {
                v.x = (col + 0 < N) ? src[0] : 0.f;
                v.y = (col + 1 < N) ? src[1] : 0.f;
                v.z = (col + 2 < N) ? src[2] : 0.f;
                v.w = (col + 3 < N) ? src[3] : 0.f;
            }
            *(float4*)&Ws[kk][wn4] = v;
        }
        __syncthreads();
        #pragma unroll
        for (int kk = 0; kk < 16; ++kk) {
            float a[8], w[8];
            *(float4*)&a[0] = *(const float4*)&As[kk][ty * 8];
            *(float4*)&a[4] = *(const float4*)&As[kk][ty * 8 + 4];
            *(float4*)&w[0] = *(const float4*)&Ws[kk][tx * 8];
            *(float4*)&w[4] = *(const float4*)&Ws[kk][tx * 8 + 4];
            #pragma unroll
            for (int i = 0; i < 8; ++i)
                #pragma unroll
                for (int j = 0; j < 8; ++j)
                    acc[i][j] = fmaf(a[i], w[j], acc[i][j]);
        }
    }

    #pragma unroll
    for (int i = 0; i < 8; ++i) {
        int m = m0 + ty * 8 + i;
        #pragma unroll
        for (int j = 0; j < 8; ++j) {
            int n = n0 + tx * 8 + j;
            if (n < N) {
                float v = acc[i][j] + (bias ? bias[n] : 0.f);
                size_t ci = (size_t)m * ldc + n;
                if (ACT == 1) {
                    v = silu_f(v);
                } else if (ACT == 2) {
                    v = (v > 20.f) ? v : log1pf(__expf(v));
                } else if (ACT == 3) {
                    v = silu_f(v) * C[ci];
                } else if (ACT == 4) {
                    int bb = m >> 10;
                    v = E0[ci] + E1[bb * H3_ + 2 * H_ + n] * v;
                }
                C[ci] = v;
            }
        }
    }
}

// ---------------------------------------------------------------------------
// K4: depthwise causal conv (KC=4) + bias + silu
// xc[b,l,d] = silu( sum_j xm[b,l-3+j,d]*conv_w[d,j] + conv_b[d] )
// xm = xz[..., 0:2048]  (xz row stride 4096)
// ---------------------------------------------------------------------------
__global__ __launch_bounds__(256) void conv_kernel(
    const float* __restrict__ xz, const float* __restrict__ conv_w,
    const float* __restrict__ conv_b, float* __restrict__ xc)
{
    size_t i = (size_t)blockIdx.x * 256 + threadIdx.x;  // B*L*DI
    int d = i & (DI_ - 1);
    size_t bl = i >> 11;            // DI = 2048
    int l = bl & (L_ - 1);
    size_t brow = bl - l;           // b*L
    float acc = conv_b[d];
    #pragma unroll
    for (int j = 0; j < KC_; ++j) {
        int ll = l - (KC_ - 1) + j;
        if (ll >= 0)
            acc = fmaf(xz[(brow + ll) * (size_t)(2 * DI_) + d], conv_w[d * KC_ + j], acc);
    }
    xc[i] = silu_f(acc);
}

// ---------------------------------------------------------------------------
// K5: selective scan, fused epilogue:
//   y2[b,l,d] = (ssm_y + xc*Dp[d]) * silu(z[b,l,d])
// grid: B * DI/256 = 32 blocks; each thread owns one (b,d) channel
// ---------------------------------------------------------------------------
__global__ __launch_bounds__(256) void scan_kernel(
    const float* __restrict__ dt, const float* __restrict__ xc,
    const float* __restrict__ xz,   /* z at cols 2048..4095 */
    const float* __restrict__ dbl,  /* Bm at 64..79, Cm at 80..95, ld 96 */
    const float* __restrict__ A_log, const float* __restrict__ Dp,
    float* __restrict__ y2)
{
    int b  = blockIdx.x >> 3;
    int d  = ((blockIdx.x & 7) << 8) + threadIdx.x;
    float Aa[NS_];
    #pragma unroll
    for (int n = 0; n < NS_; ++n) Aa[n] = -__expf(A_log[d * NS_ + n]);
    float h[NS_];
    #pragma unroll
    for (int n = 0; n < NS_; ++n) h[n] = 0.f;
    float Dpv = Dp[d];

    __shared__ float sBC[64][32];
    size_t browL = (size_t)b * L_;

    for (int l0 = 0; l0 < L_; l0 += 64) {
        __syncthreads();
        for (int idx = threadIdx.x; idx < 64 * 32; idx += 256) {
            int l = idx >> 5, n = idx & 31;
            sBC[l][n] = dbl[(browL + l0 + l) * 96 + DTR_ + n];
        }
        __syncthreads();
        for (int li = 0; li < 64; ++li) {
            size_t off = (browL + l0 + li) * (size_t)DI_ + d;
            float dtv = dt[off];
            float xv  = xc[off];
            float zv  = xz[(browL + l0 + li) * (size_t)(2 * DI_) + DI_ + d];
            float du  = dtv * xv;
            float y = 0.f;
            #pragma unroll
            for (int n = 0; n < NS_; ++n) {
                float dA = __expf(dtv * Aa[n]);
                h[n] = fmaf(dA, h[n], du * sBC[li][n]);
                y = fmaf(h[n], sBC[li][NS_ + n], y);
            }
            y = fmaf(xv, Dpv, y);
            y2[off] = y * silu_f(zv);
        }
    }
}

// ---------------------------------------------------------------------------
// launcher
// ---------------------------------------------------------------------------
extern "C" void kernel_launch(void* const* d_in, const int* in_sizes, int n_in,
                              void* d_out, int out_size, void* d_ws, size_t ws_size,
                              hipStream_t stream)
{
    const float* x         = (const float*)d_in[0];
    const float* t         = (const float*)d_in[1];
    const float* ada_w     = (const float*)d_in[2];
    const float* ada_b     = (const float*)d_in[3];
    const float* hgd_w1    = (const float*)d_in[4];
    const float* hgd_b1    = (const float*)d_in[5];
    const float* hgd_w2    = (const float*)d_in[6];
    const float* hgd_b2    = (const float*)d_in[7];
    const float* in_proj_w = (const float*)d_in[8];
    const float* conv_w    = (const float*)d_in[9];
    const float* conv_b    = (const float*)d_in[10];
    const float* x_proj_w  = (const float*)d_in[11];
    const float* dt_proj_w = (const float*)d_in[12];
    const float* dt_proj_b = (const float*)d_in[13];
    const float* A_log     = (const float*)d_in[14];
    const float* Dp        = (const float*)d_in[15];
    const float* out_proj_w= (const float*)d_in[16];
    const float* fm_w      = (const float*)d_in[17];
    const float* fm_b      = (const float*)d_in[18];
    const float* fr_w      = (const float*)d_in[19];
    const float* fr_b      = (const float*)d_in[20];
    const float* ff_w      = (const float*)d_in[21];
    const float* ff_b      = (const float*)d_in[22];
    float* out = (float*)d_out;

    float* ws = (float*)d_ws;
    float* x1   = ws;                       // 4096*1024
    float* xz   = x1   + (size_t)ROWS * H_;       // 4096*4096
    float* xc   = xz   + (size_t)ROWS * 2 * DI_;  // 4096*2048
    float* dt   = xc   + (size_t)ROWS * DI_;      // 4096*2048
    float* y2   = dt   + (size_t)ROWS * DI_;      // 4096*2048
    float* xd2  = y2   + (size_t)ROWS * DI_;      // 4096*1024 (xd, then x1_2)
    float* h1   = xd2  + (size_t)ROWS * H_;       // 4096*256  (h1, then a, then a*b)
    float* dbl  = h1   + (size_t)ROWS * HR_;      // 4096*96
    float* ada  = dbl  + (size_t)ROWS * 96;       // 4*3072

    dim3 blk(256);

    // 1. ada
    ada_kernel<<<dim3(H3_ / 256, B_), blk, 0, stream>>>(t, ada_w, ada_b, ada);
    // 2. x1 = LN(x)*(1+scale)+shift
    ln_mod_kernel<<<dim3(ROWS), blk, 0, stream>>>(x, ada, x1);
    // 3. h1 = silu(x1 @ hgd_w1 + b1)        M=4096 K=1024 N=256
    gemm_kernel<1><<<dim3(ROWS/128, 2), blk, 0, stream>>>(
        x1, H_, hgd_w1, hgd_b1, h1, HR_, ROWS, HR_, H_, nullptr, nullptr);
    // 4. xd = h1 @ hgd_w2 + b2              M=4096 K=256 N=1024
    gemm_kernel<0><<<dim3(ROWS/128, 8), blk, 0, stream>>>(
        h1, HR_, hgd_w2, hgd_b2, xd2, H_, ROWS, H_, HR_, nullptr, nullptr);
    // 5. xz = xd @ in_proj_w                M=4096 K=1024 N=4096
    gemm_kernel<0><<<dim3(ROWS/128, 32), blk, 0, stream>>>(
        xd2, H_, in_proj_w, nullptr, xz, 2 * DI_, ROWS, 2 * DI_, H_, nullptr, nullptr);
    // 6. conv + silu -> xc
    conv_kernel<<<dim3((ROWS * DI_) / 256), blk, 0, stream>>>(xz, conv_w, conv_b, xc);
    // 7. dbl = xc @ x_proj_w                M=4096 K=2048 N=96
    gemm_kernel<0><<<dim3(ROWS/128, 1), blk, 0, stream>>>(
        xc, DI_, x_proj_w, nullptr, dbl, 96, ROWS, 96, DI_, nullptr, nullptr);
    // 8. dt = softplus(dbl[:, :64] @ dt_proj_w + dt_proj_b)   M=4096 K=64 N=2048
    gemm_kernel<2><<<dim3(ROWS/128, 16), blk, 0, stream>>>(
        dbl, 96, dt_proj_w, dt_proj_b, dt, DI_, ROWS, DI_, DTR_, nullptr, nullptr);
    // 9. scan -> y2  (fused  + xc*Dp, * silu(z))
    scan_kernel<<<dim3(B_ * DI_ / 256), blk, 0, stream>>>(
        dt, xc, xz, dbl, A_log, Dp, y2);
    // 10. x1_2 = y2 @ out_proj_w            M=4096 K=2048 N=1024
    gemm_kernel<0><<<dim3(ROWS/128, 8), blk, 0, stream>>>(
        y2, DI_, out_proj_w, nullptr, xd2, H_, ROWS, H_, DI_, nullptr, nullptr);
    // 11. a = silu(x1_2 @ fm_w + fm_b)      M=4096 K=1024 N=256
    gemm_kernel<1><<<dim3(ROWS/128, 2), blk, 0, stream>>>(
        xd2, H_, fm_w, fm_b, h1, HR_, ROWS, HR_, H_, nullptr, nullptr);
    // 12. ab = silu(x1 @ fr_w + fr_b) * a   M=4096 K=1024 N=256
    gemm_kernel<3><<<dim3(ROWS/128, 2), blk, 0, stream>>>(
        x1, H_, fr_w, fr_b, h1, HR_, ROWS, HR_, H_, nullptr, nullptr);
    // 13. out = x + alpha * (ab @ ff_w + ff_b)   M=4096 K=256 N=1024
    gemm_kernel<4><<<dim3(ROWS/128, 8), blk, 0, stream>>>(
        h1, HR_, ff_w, ff_b, out, H_, ROWS, H_, HR_, x, ada);
}

// Round 2
// 822.129 us; speedup vs baseline: 3.3427x; 3.3427x over previous
//
#include <hip/hip_runtime.h>
#include <math.h>
#include <stdint.h>

#define H_   1024
#define HR_  256
#define DI_  2048
#define NS_  16
#define KC_  4
#define DTR_ 64
#define B_   4
#define L_   1024
#define ROWS (B_*L_)   // 4096
#define H3_  3072
#define NCH_ 16        // scan chunks
#define CL_  64        // chunk length

typedef short bf16x8 __attribute__((ext_vector_type(8)));
typedef float f32x4  __attribute__((ext_vector_type(4)));

__device__ __forceinline__ float silu_f(float v) { return v / (1.f + __expf(-v)); }

__device__ __forceinline__ uint32_t pack_bf16_2(float a, float b) {
    uint32_t ua = __float_as_uint(a);
    uint32_t ub = __float_as_uint(b);
    uint32_t ra = (ua + 0x7FFFu + ((ua >> 16) & 1u)) >> 16;
    uint32_t rb = (ub + 0x7FFFu + ((ub >> 16) & 1u)) >> 16;
    return ra | (rb << 16);
}

// ---------------------------------------------------------------------------
// K1: ada = silu(t) @ ada_w + ada_b      (B,3H)
// ---------------------------------------------------------------------------
__global__ __launch_bounds__(256) void ada_kernel(
    const float* __restrict__ t, const float* __restrict__ ada_w,
    const float* __restrict__ ada_b, float* __restrict__ ada)
{
    int b   = blockIdx.y;
    int col = blockIdx.x * 256 + threadIdx.x;
    __shared__ float st[H_];
    for (int i = threadIdx.x; i < H_; i += 256) {
        float v = t[b * H_ + i];
        st[i] = silu_f(v);
    }
    __syncthreads();
    float acc = 0.f;
    for (int k = 0; k < H_; ++k)
        acc = fmaf(st[k], ada_w[(size_t)k * H3_ + col], acc);
    ada[b * H3_ + col] = acc + ada_b[col];
}

// ---------------------------------------------------------------------------
// K2: x1 = LN(x) * (1+scale) + shift     (B,L,H)
// ---------------------------------------------------------------------------
__global__ __launch_bounds__(256) void ln_mod_kernel(
    const float* __restrict__ x, const float* __restrict__ ada,
    float* __restrict__ x1)
{
    int row = blockIdx.x;
    int b   = row >> 10;
    const float* xr = x + (size_t)row * H_;
    float4 v = ((const float4*)xr)[threadIdx.x];
    float s  = v.x + v.y + v.z + v.w;
    float s2 = v.x*v.x + v.y*v.y + v.z*v.z + v.w*v.w;

    __shared__ float red[8];
    int wave = threadIdx.x >> 6, lane = threadIdx.x & 63;
    #pragma unroll
    for (int off = 32; off; off >>= 1) {
        s  += __shfl_down(s,  off);
        s2 += __shfl_down(s2, off);
    }
    if (lane == 0) { red[wave] = s; red[4 + wave] = s2; }
    __syncthreads();
    float ts  = red[0] + red[1] + red[2] + red[3];
    float ts2 = red[4] + red[5] + red[6] + red[7];
    float mu  = ts  * (1.f / H_);
    float var = ts2 * (1.f / H_) - mu * mu;
    float inv = rsqrtf(var + 1e-6f);

    const float* sh = ada + b * H3_;
    int i = threadIdx.x * 4;
    float4 sh4 = *(const float4*)&sh[i];
    float4 sc4 = *(const float4*)&sh[H_ + i];
    float4 o;
    o.x = (v.x - mu) * inv * (1.f + sc4.x) + sh4.x;
    o.y = (v.y - mu) * inv * (1.f + sc4.y) + sh4.y;
    o.z = (v.z - mu) * inv * (1.f + sc4.z) + sh4.z;
    o.w = (v.w - mu) * inv * (1.f + sc4.w) + sh4.w;
    ((float4*)(x1 + (size_t)row * H_))[threadIdx.x] = o;
}

// ---------------------------------------------------------------------------
// K3: bf16-MFMA GEMM, C = act(A[M,lda](fp32) @ W[K,N](fp32) + bias)
// BM=BN=128, BK=32, 256 thr = 4 waves (2x2), 4x4 frags of 16x16x32 per wave.
// fp32->bf16 converted in-register during staging.
// ACT: 0 none, 1 silu, 2 softplus, 3 silu*C (gate), 4 out = E0 + alpha*v
// ---------------------------------------------------------------------------
template<int ACT>
__global__ __launch_bounds__(256) void mfma_gemm(
    const float* __restrict__ A, int lda,
    const float* __restrict__ W,
    const float* __restrict__ bias,
    float* __restrict__ C, int ldc,
    int M, int N, int K,
    const float* __restrict__ E0, const float* __restrict__ E1)
{
    __shared__ short As[128][32];   // [m][k] bf16
    __shared__ short Bs[128][32];   // [n][k] bf16
    int tid  = threadIdx.x;
    int m0   = blockIdx.x * 128;
    int n0   = blockIdx.y * 128;
    int lane = tid & 63, wv = tid >> 6, wm = wv >> 1, wn = wv & 1;

    f32x4 acc[4][4];
    #pragma unroll
    for (int i = 0; i < 4; ++i)
        #pragma unroll
        for (int j = 0; j < 4; ++j) {
            acc[i][j][0] = 0.f; acc[i][j][1] = 0.f;
            acc[i][j][2] = 0.f; acc[i][j][3] = 0.f;
        }

    int arow = tid >> 1;            // 0..127
    int akc  = (tid & 1) * 16;      // 0 or 16
    int bng  = tid & 31;            // n-group
    int bkb  = (tid >> 5) * 4;      // k-block 0..28
    int bcol = n0 + bng * 4;

    for (int k0 = 0; k0 < K; k0 += 32) {
        // global loads (fp32)
        const float* ap = A + (size_t)(m0 + arow) * lda + k0 + akc;
        float4 a0 = *(const float4*)(ap);
        float4 a1 = *(const float4*)(ap + 4);
        float4 a2 = *(const float4*)(ap + 8);
        float4 a3 = *(const float4*)(ap + 12);
        float4 w0, w1, w2, w3;
        if (bcol < N) {
            const float* wp = W + (size_t)(k0 + bkb) * N + bcol;
            w0 = *(const float4*)(wp);
            w1 = *(const float4*)(wp + N);
            w2 = *(const float4*)(wp + 2 * N);
            w3 = *(const float4*)(wp + 3 * N);
        } else {
            w0 = make_float4(0,0,0,0); w1 = w0; w2 = w0; w3 = w0;
        }
        __syncthreads();
        // A: row-major, k innermost
        uint4 ua0 = { pack_bf16_2(a0.x,a0.y), pack_bf16_2(a0.z,a0.w),
                      pack_bf16_2(a1.x,a1.y), pack_bf16_2(a1.z,a1.w) };
        uint4 ua1 = { pack_bf16_2(a2.x,a2.y), pack_bf16_2(a2.z,a2.w),
                      pack_bf16_2(a3.x,a3.y), pack_bf16_2(a3.z,a3.w) };
        *(uint4*)&As[arow][akc]     = ua0;
        *(uint4*)&As[arow][akc + 8] = ua1;
        // B: transpose 4x4 in-register -> Bs[n][k]
        {
            uint2 c0 = { pack_bf16_2(w0.x, w1.x), pack_bf16_2(w2.x, w3.x) };
            uint2 c1 = { pack_bf16_2(w0.y, w1.y), pack_bf16_2(w2.y, w3.y) };
            uint2 c2 = { pack_bf16_2(w0.z, w1.z), pack_bf16_2(w2.z, w3.z) };
            uint2 c3 = { pack_bf16_2(w0.w, w1.w), pack_bf16_2(w2.w, w3.w) };
            *(uint2*)&Bs[bng * 4 + 0][bkb] = c0;
            *(uint2*)&Bs[bng * 4 + 1][bkb] = c1;
            *(uint2*)&Bs[bng * 4 + 2][bkb] = c2;
            *(uint2*)&Bs[bng * 4 + 3][bkb] = c3;
        }
        __syncthreads();
        bf16x8 af[4], bfr[4];
        #pragma unroll
        for (int i = 0; i < 4; ++i)
            af[i] = *(const bf16x8*)&As[wm * 64 + i * 16 + (lane & 15)][(lane >> 4) * 8];
        #pragma unroll
        for (int j = 0; j < 4; ++j)
            bfr[j] = *(const bf16x8*)&Bs[wn * 64 + j * 16 + (lane & 15)][(lane >> 4) * 8];
        #pragma unroll
        for (int i = 0; i < 4; ++i)
            #pragma unroll
            for (int j = 0; j < 4; ++j)
                acc[i][j] = __builtin_amdgcn_mfma_f32_16x16x32_bf16(af[i], bfr[j], acc[i][j], 0, 0, 0);
    }

    // epilogue: C/D layout col=lane&15, row=(lane>>4)*4+reg
    #pragma unroll
    for (int i = 0; i < 4; ++i) {
        int mb = m0 + wm * 64 + i * 16 + ((lane >> 4) << 2);
        #pragma unroll
        for (int j = 0; j < 4; ++j) {
            int n = n0 + wn * 64 + j * 16 + (lane & 15);
            if (n < N) {
                float bv = bias ? bias[n] : 0.f;
                #pragma unroll
                for (int r = 0; r < 4; ++r) {
                    int m = mb + r;
                    float v = acc[i][j][r] + bv;
                    size_t ci = (size_t)m * ldc + n;
                    if (ACT == 1) {
                        v = silu_f(v);
                    } else if (ACT == 2) {
                        v = (v > 20.f) ? v : log1pf(__expf(v));
                    } else if (ACT == 3) {
                        v = silu_f(v) * C[ci];
                    } else if (ACT == 4) {
                        int bb = m >> 10;
                        v = E0[ci] + E1[bb * H3_ + 2 * H_ + n] * v;
                    }
                    C[ci] = v;
                }
            }
        }
    }
}

// ---------------------------------------------------------------------------
// K4: depthwise causal conv (KC=4) + bias + silu
// ---------------------------------------------------------------------------
__global__ __launch_bounds__(256) void conv_kernel(
    const float* __restrict__ xz, const float* __restrict__ conv_w,
    const float* __restrict__ conv_b, float* __restrict__ xc)
{
    size_t i = (size_t)blockIdx.x * 256 + threadIdx.x;
    int d = i & (DI_ - 1);
    size_t bl = i >> 11;
    int l = bl & (L_ - 1);
    size_t brow = bl - l;
    float acc = conv_b[d];
    #pragma unroll
    for (int j = 0; j < KC_; ++j) {
        int ll = l - (KC_ - 1) + j;
        if (ll >= 0)
            acc = fmaf(xz[(brow + ll) * (size_t)(2 * DI_) + d], conv_w[d * KC_ + j], acc);
    }
    xc[i] = silu_f(acc);
}

// ---------------------------------------------------------------------------
// K5a: chunked scan phase 1 — local scan per chunk (h_in = 0)
// grid: B*NCH*8 blocks, 256 thr; writes hend[b][c][n][d], dtsum[b][c][d]
// ---------------------------------------------------------------------------
__global__ __launch_bounds__(256) void scan_part1(
    const float* __restrict__ dt, const float* __restrict__ xc,
    const float* __restrict__ dbl, const float* __restrict__ A_log,
    float* __restrict__ hend, float* __restrict__ dtsum)
{
    int bx = blockIdx.x;
    int dg = bx & 7;
    int bc = bx >> 3;
    int c  = bc & (NCH_ - 1);
    int b  = bc >> 4;
    int d  = dg * 256 + threadIdx.x;

    float Aa[NS_];
    #pragma unroll
    for (int n = 0; n < NS_; ++n) Aa[n] = -__expf(A_log[d * NS_ + n]);

    __shared__ float sB[CL_][NS_];
    for (int idx = threadIdx.x; idx < CL_ * NS_; idx += 256) {
        int l = idx >> 4, n = idx & 15;
        sB[l][n] = dbl[(size_t)(b * L_ + c * CL_ + l) * 96 + DTR_ + n];
    }
    __syncthreads();

    float h[NS_];
    #pragma unroll
    for (int n = 0; n < NS_; ++n) h[n] = 0.f;
    float sdt = 0.f;

    for (int l = 0; l < CL_; ++l) {
        size_t off = (size_t)(b * L_ + c * CL_ + l) * DI_ + d;
        float dtv = dt[off];
        float xv  = xc[off];
        float du  = dtv * xv;
        sdt += dtv;
        #pragma unroll
        for (int n = 0; n < NS_; ++n)
            h[n] = fmaf(__expf(dtv * Aa[n]), h[n], du * sB[l][n]);
    }
    #pragma unroll
    for (int n = 0; n < NS_; ++n)
        hend[((size_t)((b * NCH_ + c) * NS_ + n)) * DI_ + d] = h[n];
    dtsum[(size_t)(b * NCH_ + c) * DI_ + d] = sdt;
}

// ---------------------------------------------------------------------------
// K5b: chunked scan phase 2 — rebuild chunk-entry state from (hend, dtsum)
// prefixes, then full scan + fused epilogue: y2 = (y + xc*Dp) * silu(z)
// ---------------------------------------------------------------------------
__global__ __launch_bounds__(256) void scan_part2(
    const float* __restrict__ dt, const float* __restrict__ xc,
    const float* __restrict__ xz, const float* __restrict__ dbl,
    const float* __restrict__ A_log, const float* __restrict__ Dp,
    const float* __restrict__ hend, const float* __restrict__ dtsum,
    float* __restrict__ y2)
{
    int bx = blockIdx.x;
    int dg = bx & 7;
    int bc = bx >> 3;
    int c  = bc & (NCH_ - 1);
    int b  = bc >> 4;
    int d  = dg * 256 + threadIdx.x;

    float Aa[NS_];
    #pragma unroll
    for (int n = 0; n < NS_; ++n) Aa[n] = -__expf(A_log[d * NS_ + n]);

    __shared__ float sBC[CL_][2 * NS_];
    for (int idx = threadIdx.x; idx < CL_ * 2 * NS_; idx += 256) {
        int l = idx >> 5, n = idx & 31;
        sBC[l][n] = dbl[(size_t)(b * L_ + c * CL_ + l) * 96 + DTR_ + n];
    }
    __syncthreads();

    // reconstruct h at chunk entry
    float h[NS_];
    #pragma unroll
    for (int n = 0; n < NS_; ++n) h[n] = 0.f;
    for (int j = 0; j < c; ++j) {
        float s = dtsum[(size_t)(b * NCH_ + j) * DI_ + d];
        #pragma unroll
        for (int n = 0; n < NS_; ++n)
            h[n] = fmaf(__expf(Aa[n] * s), h[n],
                        hend[((size_t)((b * NCH_ + j) * NS_ + n)) * DI_ + d]);
    }

    float Dpv = Dp[d];
    for (int l = 0; l < CL_; ++l) {
        size_t row = (size_t)(b * L_ + c * CL_ + l);
        size_t off = row * DI_ + d;
        float dtv = dt[off];
        float xv  = xc[off];
        float zv  = xz[row * (size_t)(2 * DI_) + DI_ + d];
        float du  = dtv * xv;
        float y = 0.f;
        #pragma unroll
        for (int n = 0; n < NS_; ++n) {
            float dA = __expf(dtv * Aa[n]);
            h[n] = fmaf(dA, h[n], du * sBC[l][n]);
            y = fmaf(h[n], sBC[l][NS_ + n], y);
        }
        y = fmaf(xv, Dpv, y);
        y2[off] = y * silu_f(zv);
    }
}

// ---------------------------------------------------------------------------
// launcher
// ---------------------------------------------------------------------------
extern "C" void kernel_launch(void* const* d_in, const int* in_sizes, int n_in,
                              void* d_out, int out_size, void* d_ws, size_t ws_size,
                              hipStream_t stream)
{
    const float* x         = (const float*)d_in[0];
    const float* t         = (const float*)d_in[1];
    const float* ada_w     = (const float*)d_in[2];
    const float* ada_b     = (const float*)d_in[3];
    const float* hgd_w1    = (const float*)d_in[4];
    const float* hgd_b1    = (const float*)d_in[5];
    const float* hgd_w2    = (const float*)d_in[6];
    const float* hgd_b2    = (const float*)d_in[7];
    const float* in_proj_w = (const float*)d_in[8];
    const float* conv_w    = (const float*)d_in[9];
    const float* conv_b    = (const float*)d_in[10];
    const float* x_proj_w  = (const float*)d_in[11];
    const float* dt_proj_w = (const float*)d_in[12];
    const float* dt_proj_b = (const float*)d_in[13];
    const float* A_log     = (const float*)d_in[14];
    const float* Dp        = (const float*)d_in[15];
    const float* out_proj_w= (const float*)d_in[16];
    const float* fm_w      = (const float*)d_in[17];
    const float* fm_b      = (const float*)d_in[18];
    const float* fr_w      = (const float*)d_in[19];
    const float* fr_b      = (const float*)d_in[20];
    const float* ff_w      = (const float*)d_in[21];
    const float* ff_b      = (const float*)d_in[22];
    float* out = (float*)d_out;

    float* ws = (float*)d_ws;
    float* x1    = ws;                              // 4096*1024
    float* xz    = x1    + (size_t)ROWS * H_;       // 4096*4096
    float* xc    = xz    + (size_t)ROWS * 2 * DI_;  // 4096*2048
    float* dt    = xc    + (size_t)ROWS * DI_;      // 4096*2048
    float* y2    = dt    + (size_t)ROWS * DI_;      // 4096*2048
    float* xd2   = y2    + (size_t)ROWS * DI_;      // 4096*1024
    float* h1    = xd2   + (size_t)ROWS * H_;       // 4096*256
    float* dbl   = h1    + (size_t)ROWS * HR_;      // 4096*96
    float* ada   = dbl   + (size_t)ROWS * 96;       // 4*3072
    float* hend  = ada   + (size_t)B_ * H3_;        // 4*16*16*2048
    float* dtsum = hend  + (size_t)B_ * NCH_ * NS_ * DI_;  // 4*16*2048

    dim3 blk(256);

    ada_kernel<<<dim3(H3_ / 256, B_), blk, 0, stream>>>(t, ada_w, ada_b, ada);
    ln_mod_kernel<<<dim3(ROWS), blk, 0, stream>>>(x, ada, x1);
    // h1 = silu(x1 @ hgd_w1 + b1)
    mfma_gemm<1><<<dim3(32, 2), blk, 0, stream>>>(
        x1, H_, hgd_w1, hgd_b1, h1, HR_, ROWS, HR_, H_, nullptr, nullptr);
    // xd = h1 @ hgd_w2 + b2
    mfma_gemm<0><<<dim3(32, 8), blk, 0, stream>>>(
        h1, HR_, hgd_w2, hgd_b2, xd2, H_, ROWS, H_, HR_, nullptr, nullptr);
    // xz = xd @ in_proj_w
    mfma_gemm<0><<<dim3(32, 32), blk, 0, stream>>>(
        xd2, H_, in_proj_w, nullptr, xz, 2 * DI_, ROWS, 2 * DI_, H_, nullptr, nullptr);
    // conv + silu -> xc
    conv_kernel<<<dim3((ROWS * DI_) / 256), blk, 0, stream>>>(xz, conv_w, conv_b, xc);
    // dbl = xc @ x_proj_w
    mfma_gemm<0><<<dim3(32, 1), blk, 0, stream>>>(
        xc, DI_, x_proj_w, nullptr, dbl, 96, ROWS, 96, DI_, nullptr, nullptr);
    // dt = softplus(dbl[:, :64] @ dt_proj_w + dt_proj_b)
    mfma_gemm<2><<<dim3(32, 16), blk, 0, stream>>>(
        dbl, 96, dt_proj_w, dt_proj_b, dt, DI_, ROWS, DI_, DTR_, nullptr, nullptr);
    // chunked scan
    scan_part1<<<dim3(B_ * NCH_ * 8), blk, 0, stream>>>(
        dt, xc, dbl, A_log, hend, dtsum);
    scan_part2<<<dim3(B_ * NCH_ * 8), blk, 0, stream>>>(
        dt, xc, xz, dbl, A_log, Dp, hend, dtsum, y2);
    // x1_2 = y2 @ out_proj_w
    mfma_gemm<0><<<dim3(32, 8), blk, 0, stream>>>(
        y2, DI_, out_proj_w, nullptr, xd2, H_, ROWS, H_, DI_, nullptr, nullptr);
    // a = silu(x1_2 @ fm_w + fm_b)
    mfma_gemm<1><<<dim3(32, 2), blk, 0, stream>>>(
        xd2, H_, fm_w, fm_b, h1, HR_, ROWS, HR_, H_, nullptr, nullptr);
    // ab = silu(x1 @ fr_w + fr_b) * a
    mfma_gemm<3><<<dim3(32, 2), blk, 0, stream>>>(
        x1, H_, fr_w, fr_b, h1, HR_, ROWS, HR_, H_, nullptr, nullptr);
    // out = x + alpha * (ab @ ff_w + ff_b)
    mfma_gemm<4><<<dim3(32, 8), blk, 0, stream>>>(
        h1, HR_, ff_w, ff_b, out, H_, ROWS, H_, HR_, x, ada);
}

// Round 3
// 564.991 us; speedup vs baseline: 4.8641x; 1.4551x over previous
//
#include <hip/hip_runtime.h>
#include <math.h>
#include <stdint.h>

#define H_   1024
#define HR_  256
#define DI_  2048
#define NS_  16
#define KC_  4
#define DTR_ 64
#define B_   4
#define L_   1024
#define ROWS (B_*L_)   // 4096
#define H3_  3072
#define NCH_ 16        // scan chunks
#define CL_  64        // chunk length
#define LDSP 40        // padded LDS row stride (shorts) = 80 B

typedef short bf16x8 __attribute__((ext_vector_type(8)));
typedef short s16x4  __attribute__((ext_vector_type(4)));
typedef float f32x4  __attribute__((ext_vector_type(4)));

__device__ __forceinline__ float silu_f(float v) { return v / (1.f + __expf(-v)); }

__device__ __forceinline__ uint32_t pack_bf16_2(float a, float b) {
    uint32_t ua = __float_as_uint(a);
    uint32_t ub = __float_as_uint(b);
    uint32_t ra = (ua + 0x7FFFu + ((ua >> 16) & 1u)) >> 16;
    uint32_t rb = (ub + 0x7FFFu + ((ub >> 16) & 1u)) >> 16;
    return ra | (rb << 16);
}
__device__ __forceinline__ unsigned short cvt_bf16(float a) {
    uint32_t ua = __float_as_uint(a);
    return (unsigned short)((ua + 0x7FFFu + ((ua >> 16) & 1u)) >> 16);
}
__device__ __forceinline__ float bf16_to_f(unsigned short u) {
    return __uint_as_float(((uint32_t)u) << 16);
}

// ---------------------------------------------------------------------------
// K0: convert all 9 GEMM weights fp32 -> bf16 arena (one kernel, if-ladder)
// ---------------------------------------------------------------------------
#define WO0 0ull
#define WO1 262144ull
#define WO2 524288ull
#define WO3 4718592ull
#define WO4 4915200ull
#define WO5 5046272ull
#define WO6 7143424ull
#define WO7 7405568ull
#define WO8 7667712ull
#define WOT 7929856ull

__global__ __launch_bounds__(256) void wconv_kernel(
    const float* __restrict__ s0, const float* __restrict__ s1,
    const float* __restrict__ s2, const float* __restrict__ s3,
    const float* __restrict__ s4, const float* __restrict__ s5,
    const float* __restrict__ s6, const float* __restrict__ s7,
    const float* __restrict__ s8, short* __restrict__ dst)
{
    size_t e = ((size_t)blockIdx.x * 256 + threadIdx.x) * 4;
    if (e >= WOT) return;
    const float* src; size_t rel;
    if      (e < WO1) { src = s0; rel = e - WO0; }
    else if (e < WO2) { src = s1; rel = e - WO1; }
    else if (e < WO3) { src = s2; rel = e - WO2; }
    else if (e < WO4) { src = s3; rel = e - WO3; }
    else if (e < WO5) { src = s4; rel = e - WO4; }
    else if (e < WO6) { src = s5; rel = e - WO5; }
    else if (e < WO7) { src = s6; rel = e - WO6; }
    else if (e < WO8) { src = s7; rel = e - WO7; }
    else              { src = s8; rel = e - WO8; }
    float4 v = *(const float4*)(src + rel);
    uint2 p = { pack_bf16_2(v.x, v.y), pack_bf16_2(v.z, v.w) };
    *(uint2*)(dst + e) = p;
}

// ---------------------------------------------------------------------------
// K1: ada = silu(t) @ ada_w + ada_b      (B,3H)  (tiny, f32)
// ---------------------------------------------------------------------------
__global__ __launch_bounds__(256) void ada_kernel(
    const float* __restrict__ t, const float* __restrict__ ada_w,
    const float* __restrict__ ada_b, float* __restrict__ ada)
{
    int b   = blockIdx.y;
    int col = blockIdx.x * 256 + threadIdx.x;
    __shared__ float st[H_];
    for (int i = threadIdx.x; i < H_; i += 256) {
        float v = t[b * H_ + i];
        st[i] = silu_f(v);
    }
    __syncthreads();
    float acc = 0.f;
    for (int k = 0; k < H_; ++k)
        acc = fmaf(st[k], ada_w[(size_t)k * H3_ + col], acc);
    ada[b * H3_ + col] = acc + ada_b[col];
}

// ---------------------------------------------------------------------------
// K2: x1 = LN(x) * (1+scale) + shift  -> bf16
// ---------------------------------------------------------------------------
__global__ __launch_bounds__(256) void ln_mod_kernel(
    const float* __restrict__ x, const float* __restrict__ ada,
    short* __restrict__ x1b)
{
    int row = blockIdx.x;
    int b   = row >> 10;
    const float* xr = x + (size_t)row * H_;
    float4 v = ((const float4*)xr)[threadIdx.x];
    float s  = v.x + v.y + v.z + v.w;
    float s2 = v.x*v.x + v.y*v.y + v.z*v.z + v.w*v.w;

    __shared__ float red[8];
    int wave = threadIdx.x >> 6, lane = threadIdx.x & 63;
    #pragma unroll
    for (int off = 32; off; off >>= 1) {
        s  += __shfl_down(s,  off);
        s2 += __shfl_down(s2, off);
    }
    if (lane == 0) { red[wave] = s; red[4 + wave] = s2; }
    __syncthreads();
    float ts  = red[0] + red[1] + red[2] + red[3];
    float ts2 = red[4] + red[5] + red[6] + red[7];
    float mu  = ts  * (1.f / H_);
    float var = ts2 * (1.f / H_) - mu * mu;
    float inv = rsqrtf(var + 1e-6f);

    const float* sh = ada + b * H3_;
    int i = threadIdx.x * 4;
    float4 sh4 = *(const float4*)&sh[i];
    float4 sc4 = *(const float4*)&sh[H_ + i];
    float ox = (v.x - mu) * inv * (1.f + sc4.x) + sh4.x;
    float oy = (v.y - mu) * inv * (1.f + sc4.y) + sh4.y;
    float oz = (v.z - mu) * inv * (1.f + sc4.z) + sh4.z;
    float ow = (v.w - mu) * inv * (1.f + sc4.w) + sh4.w;
    uint2 p = { pack_bf16_2(ox, oy), pack_bf16_2(oz, ow) };
    *(uint2*)(x1b + (size_t)row * H_ + i) = p;
}

// ---------------------------------------------------------------------------
// K3: bf16-MFMA GEMM, all-bf16 inputs, padded LDS (stride 40 shorts)
// BM=BN=128, BK=32, 256 thr = 4 waves (2x2), 4x4 frags of 16x16x32.
// ACT: 0 none, 1 silu, 2 softplus, 3 silu*G (gate), 4 E0 + alpha*v,
//      5 in_proj split (n<DI -> C f32, else Cb bf16)
// SPLITK: blockIdx.z selects K-slice of 256, writes partial C (f32).
// ---------------------------------------------------------------------------
template<int ACT, bool SPLITK>
__global__ __launch_bounds__(256) void mfma_gemm(
    const short* __restrict__ A, int lda,
    const short* __restrict__ W,
    const float* __restrict__ bias,
    float* __restrict__ C, short* __restrict__ Cb, int ldc,
    int M, int N, int K,
    const float* __restrict__ E0, const float* __restrict__ E1,
    const float* __restrict__ G)
{
    __shared__ short As[128][LDSP];
    __shared__ short Bs[128][LDSP];
    int tid  = threadIdx.x;
    int m0   = blockIdx.x * 128;
    int n0   = blockIdx.y * 128;
    int lane = tid & 63, wv = tid >> 6, wm = wv >> 1, wn = wv & 1;

    if (SPLITK) {
        int z = blockIdx.z;
        A += (size_t)z * 256;               // K-offset (columns of A)
        W += (size_t)z * 256 * N;
        C += (size_t)z * M * N;
    }

    f32x4 acc[4][4];
    #pragma unroll
    for (int i = 0; i < 4; ++i)
        #pragma unroll
        for (int j = 0; j < 4; ++j) {
            acc[i][j][0] = 0.f; acc[i][j][1] = 0.f;
            acc[i][j][2] = 0.f; acc[i][j][3] = 0.f;
        }

    int arow = tid >> 1;            // 0..127
    int akc  = (tid & 1) * 16;      // 0 or 16
    int bng  = tid & 31;            // n-group (4 cols each)
    int bkb  = (tid >> 5) * 4;      // k-block 0..28
    int bcol = n0 + bng * 4;

    for (int k0 = 0; k0 < K; k0 += 32) {
        const short* ap = A + (size_t)(m0 + arow) * lda + k0 + akc;
        bf16x8 a0 = *(const bf16x8*)(ap);
        bf16x8 a1 = *(const bf16x8*)(ap + 8);
        s16x4 w0, w1, w2, w3;
        if (bcol < N) {
            const short* wp = W + (size_t)(k0 + bkb) * N + bcol;
            w0 = *(const s16x4*)(wp);
            w1 = *(const s16x4*)(wp + N);
            w2 = *(const s16x4*)(wp + 2 * N);
            w3 = *(const s16x4*)(wp + 3 * N);
        } else {
            w0 = (s16x4)0; w1 = (s16x4)0; w2 = (s16x4)0; w3 = (s16x4)0;
        }
        __syncthreads();
        *(bf16x8*)&As[arow][akc]     = a0;
        *(bf16x8*)&As[arow][akc + 8] = a1;
        #pragma unroll
        for (int j = 0; j < 4; ++j) {
            s16x4 col = { w0[j], w1[j], w2[j], w3[j] };
            *(s16x4*)&Bs[bng * 4 + j][bkb] = col;
        }
        __syncthreads();
        bf16x8 af[4], bfr[4];
        #pragma unroll
        for (int i = 0; i < 4; ++i)
            af[i] = *(const bf16x8*)&As[wm * 64 + i * 16 + (lane & 15)][(lane >> 4) * 8];
        #pragma unroll
        for (int j = 0; j < 4; ++j)
            bfr[j] = *(const bf16x8*)&Bs[wn * 64 + j * 16 + (lane & 15)][(lane >> 4) * 8];
        #pragma unroll
        for (int i = 0; i < 4; ++i)
            #pragma unroll
            for (int j = 0; j < 4; ++j)
                acc[i][j] = __builtin_amdgcn_mfma_f32_16x16x32_bf16(af[i], bfr[j], acc[i][j], 0, 0, 0);
    }

    // epilogue: C/D layout col=lane&15, row=(lane>>4)*4+reg
    #pragma unroll
    for (int i = 0; i < 4; ++i) {
        int mb = m0 + wm * 64 + i * 16 + ((lane >> 4) << 2);
        #pragma unroll
        for (int j = 0; j < 4; ++j) {
            int n = n0 + wn * 64 + j * 16 + (lane & 15);
            if (n < N) {
                float bv = bias ? bias[n] : 0.f;
                #pragma unroll
                for (int r = 0; r < 4; ++r) {
                    int m = mb + r;
                    float v = acc[i][j][r] + bv;
                    size_t ci = (size_t)m * ldc + n;
                    if (ACT == 5) {
                        if (n < DI_) C[(size_t)m * DI_ + n] = v;
                        else         Cb[(size_t)m * DI_ + n - DI_] = cvt_bf16(v);
                    } else {
                        if (ACT == 1) v = silu_f(v);
                        else if (ACT == 2) v = (v > 20.f) ? v : log1pf(__expf(v));
                        else if (ACT == 3) v = silu_f(v) * G[ci];
                        else if (ACT == 4) {
                            int bb = m >> 10;
                            v = E0[ci] + E1[bb * H3_ + 2 * H_ + n] * v;
                        }
                        if (C)  C[ci]  = v;
                        if (Cb) Cb[ci] = cvt_bf16(v);
                    }
                }
            }
        }
    }
}

// ---------------------------------------------------------------------------
// K3b: splitK reduce: dbl = sum_z part[z], also bf16 copy
// ---------------------------------------------------------------------------
__global__ __launch_bounds__(256) void redk_kernel(
    const float* __restrict__ part, float* __restrict__ dbl,
    short* __restrict__ dblb)
{
    size_t i = ((size_t)blockIdx.x * 256 + threadIdx.x) * 4;
    const size_t seg = (size_t)ROWS * 96;
    float4 s = *(const float4*)(part + i);
    #pragma unroll
    for (int z = 1; z < 8; ++z) {
        float4 p = *(const float4*)(part + z * seg + i);
        s.x += p.x; s.y += p.y; s.z += p.z; s.w += p.w;
    }
    *(float4*)(dbl + i) = s;
    uint2 p = { pack_bf16_2(s.x, s.y), pack_bf16_2(s.z, s.w) };
    *(uint2*)(dblb + i) = p;
}

// ---------------------------------------------------------------------------
// K4: depthwise causal conv (KC=4) + bias + silu -> xc f32 + xcb bf16
// ---------------------------------------------------------------------------
__global__ __launch_bounds__(256) void conv_kernel(
    const float* __restrict__ xm, const float* __restrict__ conv_w,
    const float* __restrict__ conv_b, float* __restrict__ xc,
    short* __restrict__ xcb)
{
    size_t i = (size_t)blockIdx.x * 256 + threadIdx.x;
    int d = i & (DI_ - 1);
    size_t bl = i >> 11;
    int l = bl & (L_ - 1);
    size_t brow = bl - l;
    float acc = conv_b[d];
    #pragma unroll
    for (int j = 0; j < KC_; ++j) {
        int ll = l - (KC_ - 1) + j;
        if (ll >= 0)
            acc = fmaf(xm[(brow + ll) * (size_t)DI_ + d], conv_w[d * KC_ + j], acc);
    }
    float v = silu_f(acc);
    xc[i]  = v;
    xcb[i] = (short)cvt_bf16(v);
}

// ---------------------------------------------------------------------------
// K5a: chunked scan phase 1
// ---------------------------------------------------------------------------
__global__ __launch_bounds__(256) void scan_part1(
    const float* __restrict__ dt, const float* __restrict__ xc,
    const float* __restrict__ dbl, const float* __restrict__ A_log,
    float* __restrict__ hend, float* __restrict__ dtsum)
{
    int bx = blockIdx.x;
    int dg = bx & 7;
    int bc = bx >> 3;
    int c  = bc & (NCH_ - 1);
    int b  = bc >> 4;
    int d  = dg * 256 + threadIdx.x;

    float Aa[NS_];
    #pragma unroll
    for (int n = 0; n < NS_; ++n) Aa[n] = -__expf(A_log[d * NS_ + n]);

    __shared__ float sB[CL_][NS_];
    for (int idx = threadIdx.x; idx < CL_ * NS_; idx += 256) {
        int l = idx >> 4, n = idx & 15;
        sB[l][n] = dbl[(size_t)(b * L_ + c * CL_ + l) * 96 + DTR_ + n];
    }
    __syncthreads();

    float h[NS_];
    #pragma unroll
    for (int n = 0; n < NS_; ++n) h[n] = 0.f;
    float sdt = 0.f;

    for (int l = 0; l < CL_; ++l) {
        size_t off = (size_t)(b * L_ + c * CL_ + l) * DI_ + d;
        float dtv = dt[off];
        float xv  = xc[off];
        float du  = dtv * xv;
        sdt += dtv;
        #pragma unroll
        for (int n = 0; n < NS_; ++n)
            h[n] = fmaf(__expf(dtv * Aa[n]), h[n], du * sB[l][n]);
    }
    #pragma unroll
    for (int n = 0; n < NS_; ++n)
        hend[((size_t)((b * NCH_ + c) * NS_ + n)) * DI_ + d] = h[n];
    dtsum[(size_t)(b * NCH_ + c) * DI_ + d] = sdt;
}

// ---------------------------------------------------------------------------
// K5b: chunked scan phase 2 + epilogue y2 = (y + xc*Dp)*silu(z) -> bf16
// ---------------------------------------------------------------------------
__global__ __launch_bounds__(256) void scan_part2(
    const float* __restrict__ dt, const float* __restrict__ xc,
    const short* __restrict__ zb, const float* __restrict__ dbl,
    const float* __restrict__ A_log, const float* __restrict__ Dp,
    const float* __restrict__ hend, const float* __restrict__ dtsum,
    short* __restrict__ y2b)
{
    int bx = blockIdx.x;
    int dg = bx & 7;
    int bc = bx >> 3;
    int c  = bc & (NCH_ - 1);
    int b  = bc >> 4;
    int d  = dg * 256 + threadIdx.x;

    float Aa[NS_];
    #pragma unroll
    for (int n = 0; n < NS_; ++n) Aa[n] = -__expf(A_log[d * NS_ + n]);

    __shared__ float sBC[CL_][2 * NS_];
    for (int idx = threadIdx.x; idx < CL_ * 2 * NS_; idx += 256) {
        int l = idx >> 5, n = idx & 31;
        sBC[l][n] = dbl[(size_t)(b * L_ + c * CL_ + l) * 96 + DTR_ + n];
    }
    __syncthreads();

    float h[NS_];
    #pragma unroll
    for (int n = 0; n < NS_; ++n) h[n] = 0.f;
    for (int j = 0; j < c; ++j) {
        float s = dtsum[(size_t)(b * NCH_ + j) * DI_ + d];
        #pragma unroll
        for (int n = 0; n < NS_; ++n)
            h[n] = fmaf(__expf(Aa[n] * s), h[n],
                        hend[((size_t)((b * NCH_ + j) * NS_ + n)) * DI_ + d]);
    }

    float Dpv = Dp[d];
    for (int l = 0; l < CL_; ++l) {
        size_t row = (size_t)(b * L_ + c * CL_ + l);
        size_t off = row * DI_ + d;
        float dtv = dt[off];
        float xv  = xc[off];
        float zv  = bf16_to_f((unsigned short)zb[off]);
        float du  = dtv * xv;
        float y = 0.f;
        #pragma unroll
        for (int n = 0; n < NS_; ++n) {
            float dA = __expf(dtv * Aa[n]);
            h[n] = fmaf(dA, h[n], du * sBC[l][n]);
            y = fmaf(h[n], sBC[l][NS_ + n], y);
        }
        y = fmaf(xv, Dpv, y);
        y2b[off] = (short)cvt_bf16(y * silu_f(zv));
    }
}

// ---------------------------------------------------------------------------
// launcher
// ---------------------------------------------------------------------------
extern "C" void kernel_launch(void* const* d_in, const int* in_sizes, int n_in,
                              void* d_out, int out_size, void* d_ws, size_t ws_size,
                              hipStream_t stream)
{
    const float* x         = (const float*)d_in[0];
    const float* t         = (const float*)d_in[1];
    const float* ada_w     = (const float*)d_in[2];
    const float* ada_b     = (const float*)d_in[3];
    const float* hgd_w1    = (const float*)d_in[4];
    const float* hgd_b1    = (const float*)d_in[5];
    const float* hgd_w2    = (const float*)d_in[6];
    const float* hgd_b2    = (const float*)d_in[7];
    const float* in_proj_w = (const float*)d_in[8];
    const float* conv_w    = (const float*)d_in[9];
    const float* conv_b    = (const float*)d_in[10];
    const float* x_proj_w  = (const float*)d_in[11];
    const float* dt_proj_w = (const float*)d_in[12];
    const float* dt_proj_b = (const float*)d_in[13];
    const float* A_log     = (const float*)d_in[14];
    const float* Dp        = (const float*)d_in[15];
    const float* out_proj_w= (const float*)d_in[16];
    const float* fm_w      = (const float*)d_in[17];
    const float* fm_b      = (const float*)d_in[18];
    const float* fr_w      = (const float*)d_in[19];
    const float* fr_b      = (const float*)d_in[20];
    const float* ff_w      = (const float*)d_in[21];
    const float* ff_b      = (const float*)d_in[22];
    float* out = (float*)d_out;

    char* p = (char*)d_ws;
    auto alloc = [&](size_t bytes) { char* r = p; p += (bytes + 255) & ~255ull; return r; };

    short* wb    = (short*)alloc(WOT * 2);                      // 15.9 MB
    short* x1b   = (short*)alloc((size_t)ROWS * H_ * 2);        // 8 MB
    short* h1b   = (short*)alloc((size_t)ROWS * HR_ * 2);       // 2 MB (later abb)
    short* xdb   = (short*)alloc((size_t)ROWS * H_ * 2);        // 8 MB
    float* xm    = (float*)alloc((size_t)ROWS * DI_ * 4);       // 32 MB
    short* zb    = (short*)alloc((size_t)ROWS * DI_ * 2);       // 16 MB
    float* xc    = (float*)alloc((size_t)ROWS * DI_ * 4);       // 32 MB
    short* xcb   = (short*)alloc((size_t)ROWS * DI_ * 2);       // 16 MB (later y2b)
    float* dt    = (float*)alloc((size_t)ROWS * DI_ * 4);       // 32 MB (earlier: splitK part)
    float* dbl   = (float*)alloc((size_t)ROWS * 96 * 4);        // 1.5 MB
    short* dblb  = (short*)alloc((size_t)ROWS * 96 * 2);        // 0.75 MB
    short* x12b  = (short*)alloc((size_t)ROWS * H_ * 2);        // 8 MB (earlier: hend)
    float* afp   = (float*)alloc((size_t)ROWS * HR_ * 4);       // 4 MB (earlier: dtsum)
    float* ada   = (float*)alloc((size_t)B_ * H3_ * 4);

    float* part  = dt;                  // [8][4096][96] f32 = 12.6 MB <= 32 MB
    float* hend  = (float*)x12b;        // 8 MB exactly
    float* dtsum = afp;                 // 0.5 MB <= 4 MB
    short* y2b   = xcb;                 // 16 MB, xcb dead after x_proj
    short* abb   = h1b;                 // 2 MB, h1b dead after hgd2

    short* hgd_w1b  = wb + WO0;
    short* hgd_w2b  = wb + WO1;
    short* in_projb = wb + WO2;
    short* x_projb  = wb + WO3;
    short* dt_projb = wb + WO4;
    short* out_projb= wb + WO5;
    short* fmb      = wb + WO6;
    short* frb      = wb + WO7;
    short* ffb      = wb + WO8;

    dim3 blk(256);

    wconv_kernel<<<dim3((WOT / 4 + 255) / 256), blk, 0, stream>>>(
        hgd_w1, hgd_w2, in_proj_w, x_proj_w, dt_proj_w, out_proj_w,
        fm_w, fr_w, ff_w, wb);
    ada_kernel<<<dim3(H3_ / 256, B_), blk, 0, stream>>>(t, ada_w, ada_b, ada);
    ln_mod_kernel<<<dim3(ROWS), blk, 0, stream>>>(x, ada, x1b);
    // h1 = silu(x1 @ hgd_w1 + b1) -> bf16
    mfma_gemm<1, false><<<dim3(32, 2), blk, 0, stream>>>(
        x1b, H_, hgd_w1b, hgd_b1, nullptr, h1b, HR_, ROWS, HR_, H_, nullptr, nullptr, nullptr);
    // xd = h1 @ hgd_w2 + b2 -> bf16
    mfma_gemm<0, false><<<dim3(32, 8), blk, 0, stream>>>(
        h1b, HR_, hgd_w2b, hgd_b2, nullptr, xdb, H_, ROWS, H_, HR_, nullptr, nullptr, nullptr);
    // xz = xd @ in_proj_w : xm f32, z bf16
    mfma_gemm<5, false><<<dim3(32, 32), blk, 0, stream>>>(
        xdb, H_, in_projb, nullptr, xm, zb, 2 * DI_, ROWS, 2 * DI_, H_, nullptr, nullptr, nullptr);
    // conv + silu -> xc f32 + xcb bf16
    conv_kernel<<<dim3((ROWS * DI_) / 256), blk, 0, stream>>>(xm, conv_w, conv_b, xc, xcb);
    // dbl partials = xc @ x_proj_w  (splitK=8)
    mfma_gemm<0, true><<<dim3(32, 1, 8), blk, 0, stream>>>(
        xcb, DI_, x_projb, nullptr, part, nullptr, 96, ROWS, 96, 256, nullptr, nullptr, nullptr);
    redk_kernel<<<dim3(ROWS * 96 / 4 / 256), blk, 0, stream>>>(part, dbl, dblb);
    // dt = softplus(dbl[:, :64] @ dt_proj_w + dt_proj_b) -> f32
    mfma_gemm<2, false><<<dim3(32, 16), blk, 0, stream>>>(
        dblb, 96, dt_projb, dt_proj_b, dt, nullptr, DI_, ROWS, DI_, DTR_, nullptr, nullptr, nullptr);
    // chunked scan
    scan_part1<<<dim3(B_ * NCH_ * 8), blk, 0, stream>>>(
        dt, xc, dbl, A_log, hend, dtsum);
    scan_part2<<<dim3(B_ * NCH_ * 8), blk, 0, stream>>>(
        dt, xc, zb, dbl, A_log, Dp, hend, dtsum, y2b);
    // x1_2 = y2 @ out_proj_w -> bf16
    mfma_gemm<0, false><<<dim3(32, 8), blk, 0, stream>>>(
        y2b, DI_, out_projb, nullptr, nullptr, x12b, H_, ROWS, H_, DI_, nullptr, nullptr, nullptr);
    // a = silu(x1_2 @ fm_w + fm_b) -> f32
    mfma_gemm<1, false><<<dim3(32, 2), blk, 0, stream>>>(
        x12b, H_, fmb, fm_b, afp, nullptr, HR_, ROWS, HR_, H_, nullptr, nullptr, nullptr);
    // ab = silu(x1 @ fr_w + fr_b) * a -> bf16
    mfma_gemm<3, false><<<dim3(32, 2), blk, 0, stream>>>(
        x1b, H_, frb, fr_b, nullptr, abb, HR_, ROWS, HR_, H_, nullptr, nullptr, afp);
    // out = x + alpha * (ab @ ff_w + ff_b)
    mfma_gemm<4, false><<<dim3(32, 8), blk, 0, stream>>>(
        abb, HR_, ffb, ff_b, out, nullptr, H_, ROWS, H_, HR_, x, ada, nullptr);
}